// Round 1
// baseline (347.793 us; speedup 1.0000x reference)
//
#include <hip/hip_runtime.h>
#include <stdint.h>

// Problem shape (fixed by reference setup_inputs): out = x @ W^T + bias, all fp32.
// float_quantize(exp=8,man=23) is an identity on fp32, so this is a plain fp32 GEMM.
// Strategy: split-bf16 emulation (hi+lo, 3 MFMA products) on the matrix cores.
#define MM 8192
#define KK 1024
#define NN 4096

#define BM 128
#define BN 128
#define BK 64

using f32x4 = __attribute__((ext_vector_type(4))) float;
using u16x8 = __attribute__((ext_vector_type(8))) unsigned short;

static __device__ __forceinline__ unsigned short f2bf(float f) {
    // round-to-nearest-even fp32 -> bf16 (finite inputs only; no NaN/Inf in this problem)
    unsigned int u = __builtin_bit_cast(unsigned int, f);
    u += 0x7fffu + ((u >> 16) & 1u);
    return (unsigned short)(u >> 16);
}
static __device__ __forceinline__ float bf2f(unsigned short s) {
    unsigned int u = ((unsigned int)s) << 16;
    return __builtin_bit_cast(float, u);
}

// ---------------------------------------------------------------------------
// Split fp32 array into hi/lo bf16 arrays. hi = bf16(v); lo = bf16(v - hi).
// (subtraction is exact by Sterbenz; hi+lo carries ~16 mantissa bits)
// ---------------------------------------------------------------------------
__global__ __launch_bounds__(256) void split_hi_lo(const float* __restrict__ in,
                                                   unsigned short* __restrict__ hi,
                                                   unsigned short* __restrict__ lo,
                                                   int n8) {
    int i = blockIdx.x * 256 + threadIdx.x;
    if (i >= n8) return;
    const float4* p = (const float4*)in + (size_t)i * 2;
    float4 a = p[0], b = p[1];
    float v[8] = {a.x, a.y, a.z, a.w, b.x, b.y, b.z, b.w};
    u16x8 h, l;
#pragma unroll
    for (int j = 0; j < 8; ++j) {
        unsigned short hb = f2bf(v[j]);
        h[j] = hb;
        l[j] = f2bf(v[j] - bf2f(hb));
    }
    *((u16x8*)hi + i) = h;
    *((u16x8*)lo + i) = l;
}

// ---------------------------------------------------------------------------
// Split-bf16 MFMA GEMM: C = Ahi*Bhi + Alo*Bhi + Ahi*Blo (+bias)
// A = x[M][K], B = W[N][K] (both K-contiguous). 128x128 tile, BK=64,
// 4 waves of 64x64, 16x16x32 bf16 MFMA (3 products per fragment pair).
// LDS XOR-swizzle (byte ^= (row&7)<<4) on write and read to kill the
// 32-way conflict of a 128B-stride row-major tile (Guideline 4).
// Inline-asm MFMA to avoid builtin-signature ambiguity.
// ---------------------------------------------------------------------------
static __device__ __forceinline__ void mfma16(f32x4& d, u16x8 a, u16x8 b) {
    asm("v_mfma_f32_16x16x32_bf16 %0, %1, %2, %0" : "+v"(d) : "v"(a), "v"(b));
}

__global__ __launch_bounds__(256, 2) void qlinear_mfma(
        const unsigned short* __restrict__ Ah, const unsigned short* __restrict__ Al,
        const unsigned short* __restrict__ Bh, const unsigned short* __restrict__ Bl,
        const float* __restrict__ bias, float* __restrict__ out) {
    __shared__ __attribute__((aligned(16))) unsigned short sAh[BM * BK];
    __shared__ __attribute__((aligned(16))) unsigned short sAl[BM * BK];
    __shared__ __attribute__((aligned(16))) unsigned short sBh[BN * BK];
    __shared__ __attribute__((aligned(16))) unsigned short sBl[BN * BK];

    // XCD-aware swizzle: 2048 blocks % 8 == 0 -> simple variant is bijective.
    // Chunk of 256 consecutive wg per XCD shares 4 B-panels (2 MB, L2-resident).
    int bid = blockIdx.x;
    int wg = (bid & 7) * 256 + (bid >> 3);
    int bm = wg & 63;   // M tile index (64 tiles)
    int bn = wg >> 6;   // N tile index (32 tiles)

    const int t = threadIdx.x;
    const int lane = t & 63;
    const int wid = t >> 6;

    const int wr = (wid >> 1) * 64;  // wave row offset in tile
    const int wc = (wid & 1) * 64;   // wave col offset in tile
    const int lr = lane & 15;
    const int lg = lane >> 4;

    f32x4 acc[4][4] = {};

    for (int kt = 0; kt < KK; kt += BK) {
        __syncthreads();
        // ---- stage 4 tiles (reg-staged, swizzled ds_write_b128) ----
#pragma unroll
        for (int i = 0; i < 4; ++i) {
            int o = i * 256 + t;           // octet index 0..1023
            int row = o >> 3;              // 0..127
            int k0 = (o & 7) * 8;          // 0..56
            int sidx = row * BK + (k0 ^ ((row & 7) << 3));  // element-index swizzle
            size_t ga = (size_t)(bm * BM + row) * KK + kt + k0;
            size_t gb = (size_t)(bn * BN + row) * KK + kt + k0;
            *(u16x8*)(sAh + sidx) = *(const u16x8*)(Ah + ga);
            *(u16x8*)(sAl + sidx) = *(const u16x8*)(Al + ga);
            *(u16x8*)(sBh + sidx) = *(const u16x8*)(Bh + gb);
            *(u16x8*)(sBl + sidx) = *(const u16x8*)(Bl + gb);
        }
        __syncthreads();

        // ---- compute: 2 x (16 frag reads + 48 MFMAs) per wave ----
#pragma unroll
        for (int kk = 0; kk < 2; ++kk) {
            const int kb = kk * 32 + lg * 8;  // this lane's k-base within BK
            u16x8 ah[4], al[4], bh[4], bl[4];
#pragma unroll
            for (int mi = 0; mi < 4; ++mi) {
                int row = wr + mi * 16 + lr;
                int idx = row * BK + (kb ^ ((row & 7) << 3));
                ah[mi] = *(const u16x8*)(sAh + idx);
                al[mi] = *(const u16x8*)(sAl + idx);
            }
#pragma unroll
            for (int ni = 0; ni < 4; ++ni) {
                int row = wc + ni * 16 + lr;
                int idx = row * BK + (kb ^ ((row & 7) << 3));
                bh[ni] = *(const u16x8*)(sBh + idx);
                bl[ni] = *(const u16x8*)(sBl + idx);
            }
#pragma unroll
            for (int mi = 0; mi < 4; ++mi) {
#pragma unroll
                for (int ni = 0; ni < 4; ++ni) {
                    mfma16(acc[mi][ni], ah[mi], bh[ni]);  // hi*hi
                    mfma16(acc[mi][ni], al[mi], bh[ni]);  // lo*hi
                    mfma16(acc[mi][ni], ah[mi], bl[ni]);  // hi*lo
                }
            }
        }
    }

    // ---- epilogue: C/D layout col=lane&15, row=(lane>>4)*4+reg (m89-verified) ----
    const int colbase = bn * BN + wc;
    const int rowbase = bm * BM + wr;
    float bv[4];
#pragma unroll
    for (int ni = 0; ni < 4; ++ni) bv[ni] = bias[colbase + ni * 16 + lr];
#pragma unroll
    for (int mi = 0; mi < 4; ++mi) {
#pragma unroll
        for (int ni = 0; ni < 4; ++ni) {
            int col = colbase + ni * 16 + lr;
            size_t base = (size_t)(rowbase + mi * 16 + lg * 4) * NN + col;
#pragma unroll
            for (int r = 0; r < 4; ++r)
                out[base + (size_t)r * NN] = acc[mi][ni][r] + bv[ni];
        }
    }
}

// ---------------------------------------------------------------------------
// Fallback (only if d_ws is too small for the split arrays): naive fp32 GEMM.
// ---------------------------------------------------------------------------
__global__ __launch_bounds__(256) void qlinear_naive(const float* __restrict__ x,
                                                     const float* __restrict__ w,
                                                     const float* __restrict__ bias,
                                                     float* __restrict__ out) {
    int n = blockIdx.x * 64 + (threadIdx.x & 63);
    int m = blockIdx.y * 4 + (threadIdx.x >> 6);
    const float4* xr = (const float4*)(x + (size_t)m * KK);
    const float4* wr = (const float4*)(w + (size_t)n * KK);
    float s = 0.f;
    for (int k = 0; k < KK / 4; ++k) {
        float4 a = xr[k], b = wr[k];
        s += a.x * b.x + a.y * b.y + a.z * b.z + a.w * b.w;
    }
    out[(size_t)m * NN + n] = s + bias[n];
}

extern "C" void kernel_launch(void* const* d_in, const int* in_sizes, int n_in,
                              void* d_out, int out_size, void* d_ws, size_t ws_size,
                              hipStream_t stream) {
    (void)in_sizes; (void)n_in; (void)out_size;
    const float* x = (const float*)d_in[0];
    const float* w = (const float*)d_in[1];
    const float* bias = (const float*)d_in[2];
    float* out = (float*)d_out;

    const size_t xcnt = (size_t)MM * KK;  // 8,388,608
    const size_t wcnt = (size_t)NN * KK;  // 4,194,304
    const size_t need = (xcnt + wcnt) * 2 * sizeof(unsigned short);  // 48 MiB

    if (ws_size >= need) {
        unsigned short* xh = (unsigned short*)d_ws;
        unsigned short* xl = xh + xcnt;
        unsigned short* wh = xl + xcnt;
        unsigned short* wl = wh + wcnt;
        split_hi_lo<<<(int)(xcnt / 8 / 256), 256, 0, stream>>>(x, xh, xl, (int)(xcnt / 8));
        split_hi_lo<<<(int)(wcnt / 8 / 256), 256, 0, stream>>>(w, wh, wl, (int)(wcnt / 8));
        qlinear_mfma<<<2048, 256, 0, stream>>>(xh, xl, wh, wl, bias, out);
    } else {
        dim3 grid(NN / 64, MM / 4);
        qlinear_naive<<<grid, 256, 0, stream>>>(x, w, bias, out);
    }
}

// Round 2
// 335.287 us; speedup vs baseline: 1.0373x; 1.0373x over previous
//
#include <hip/hip_runtime.h>
#include <stdint.h>

// out[8192,4096] = x[8192,1024] @ W[4096,1024]^T + bias  (all fp32; float_quantize
// with exp=8/man=23 is an identity). Split-bf16 emulation: 3 MFMA products
// (hi*hi + lo*hi + hi*lo), fp32 accumulate.
#define MM 8192
#define KK 1024
#define NN 4096
#define NT 32          // K tiles (BK=32)
#define TE 8192        // elems per plane-tile (256 rows x 32 k)
#define PL 16384       // plane stride in LDS bytes (TE * 2)

typedef float f32x4 __attribute__((ext_vector_type(4)));
typedef __bf16 bf16x8 __attribute__((ext_vector_type(8)));
typedef unsigned short u16x8 __attribute__((ext_vector_type(8)));

static __device__ __forceinline__ unsigned short f2bf(float f) {
    unsigned int u = __builtin_bit_cast(unsigned int, f);
    u += 0x7fffu + ((u >> 16) & 1u);   // RNE fp32 -> bf16 (finite inputs)
    return (unsigned short)(u >> 16);
}
static __device__ __forceinline__ float bf2f(unsigned short s) {
    unsigned int u = ((unsigned int)s) << 16;
    return __builtin_bit_cast(float, u);
}

// ---------------------------------------------------------------------------
// Split fp32 -> (hi,lo) bf16 planes, written PRE-TILED in the exact linear
// order the GEMM's global_load_lds staging wants, with the bank-spread
// permutation applied (rule 21: linear LDS dest + pre-permuted source).
// Tile (bt,kt) = 256 rows x 32 k. Element (r,k): oct=k>>3,
// slot = r*4 + (oct ^ ((r>>1)&3)); elem pos = tilebase + slot*8 + (k&7).
// ---------------------------------------------------------------------------
__global__ __launch_bounds__(256) void split_pack(const float* __restrict__ in,
        unsigned short* __restrict__ hi, unsigned short* __restrict__ lo, int total) {
    int i = blockIdx.x * 256 + threadIdx.x;     // one thread per k-octet
    if (i >= total) return;
    int row = i >> 7;                            // KK/8 = 128 octets per row
    int og  = i & 127;
    int kt  = og >> 2, oct = og & 3;
    int bt  = row >> 8, r = row & 255;
    const float4* s = (const float4*)(in + (size_t)row * KK + kt * 32 + oct * 8);
    float4 a = s[0], b = s[1];
    float v[8] = {a.x, a.y, a.z, a.w, b.x, b.y, b.z, b.w};
    u16x8 h, l;
#pragma unroll
    for (int j = 0; j < 8; ++j) {
        unsigned short hb = f2bf(v[j]);
        h[j] = hb;
        l[j] = f2bf(v[j] - bf2f(hb));            // v - hi exact; lo carries ~8 more bits
    }
    int slot = r * 4 + (oct ^ ((r >> 1) & 3));
    size_t off = (size_t)(bt * NT + kt) * TE + (size_t)slot * 8;
    *(u16x8*)(hi + off) = h;
    *(u16x8*)(lo + off) = l;
}

// ---------------------------------------------------------------------------
// helpers
// ---------------------------------------------------------------------------
static __device__ __forceinline__ bf16x8 ldsr(unsigned addr) {
    bf16x8 r;
    asm volatile("ds_read_b128 %0, %1" : "=v"(r) : "v"(addr));
    return r;
}
static __device__ __forceinline__ void gl16(const unsigned short* g, unsigned short* l) {
    __builtin_amdgcn_global_load_lds(
        (__attribute__((address_space(1))) void*)(void*)g,
        (__attribute__((address_space(3))) void*)(void*)l, 16, 0, 0);
}
static __device__ __forceinline__ void mf(f32x4& d, bf16x8 a, bf16x8 b) {
    d = __builtin_amdgcn_mfma_f32_16x16x32_bf16(a, b, d, 0, 0, 0);
}

#define PHASE_PRE() \
    __builtin_amdgcn_s_barrier(); \
    asm volatile("s_waitcnt lgkmcnt(0)" ::: "memory"); \
    __builtin_amdgcn_sched_barrier(0); \
    __builtin_amdgcn_s_setprio(1);
#define PHASE_POST() \
    __builtin_amdgcn_s_setprio(0); \
    __builtin_amdgcn_s_barrier();
#define CLUSTER(M0, M1) \
    _Pragma("unroll") \
    for (int ni = 0; ni < 4; ++ni) { \
        mf(acc[M0][ni], a0, bh[ni]); mf(acc[M0][ni], l0, bh[ni]); mf(acc[M0][ni], a0, blo[ni]); \
        mf(acc[M1][ni], a1, bh[ni]); mf(acc[M1][ni], l1, bh[ni]); mf(acc[M1][ni], a1, blo[ni]); \
    }

// ---------------------------------------------------------------------------
// 256x256 tile, BK=32, 8 waves (2M x 4N, 128x64 per wave), double-buffered LDS
// (2 x 4 planes x 16KB = 128 KiB), global_load_lds staging from pre-arranged
// planes, 4-phase/K-tile schedule with setprio'd MFMA clusters.
// ---------------------------------------------------------------------------
__global__ __launch_bounds__(512, 2) void qlinear_mfma(
        const unsigned short* __restrict__ Ah, const unsigned short* __restrict__ Al,
        const unsigned short* __restrict__ Bh, const unsigned short* __restrict__ Bl,
        const float* __restrict__ bias, float* __restrict__ out) {
    __shared__ __attribute__((aligned(16))) unsigned short S[2][4][TE];

    // XCD-bijective swizzle: grid=512, 64 consecutive wg per XCD share B-panels.
    int bid = blockIdx.x;
    int wg = (bid & 7) * 64 + (bid >> 3);
    int bm = wg & 31, bn = wg >> 5;              // 32 x 16 tiles

    const int tix = threadIdx.x;
    const int lane = tix & 63, wid = tix >> 6;
    const int wr = (wid >> 2) * 128, wc = (wid & 3) * 64;
    const int lr = lane & 15, lg = lane >> 4;
    const int xorv = (lr >> 1) & 3;              // row bits 1-2 == lr bits 1-2

    const unsigned lb = (unsigned)(uintptr_t)(__attribute__((address_space(3))) void*)&S[0][0][0];
    const unsigned pA = lb + (unsigned)(((wr + lr) * 32 + (lg ^ xorv) * 8) * 2);
    const unsigned pB = lb + (unsigned)(((wc + lr) * 32 + (lg ^ xorv) * 8) * 2);

    // staging: per-wave 2KB chunk of each 16KB plane; per-lane 16B
    const int soff = wid * 1024 + lane * 8;      // element units
    const unsigned short* sAh = Ah + (size_t)bm * NT * TE + soff;
    const unsigned short* sAl = Al + (size_t)bm * NT * TE + soff;
    const unsigned short* sBh = Bh + (size_t)bn * NT * TE + soff;
    const unsigned short* sBl = Bl + (size_t)bn * NT * TE + soff;

    f32x4 acc[8][4];
#pragma unroll
    for (int mi = 0; mi < 8; ++mi)
#pragma unroll
        for (int ni = 0; ni < 4; ++ni) acc[mi][ni] = (f32x4){0.f, 0.f, 0.f, 0.f};

    // prologue: stage tile 0 -> buf 0
    gl16(sAh,       &S[0][0][wid * 1024]);
    gl16(sAh + 512, &S[0][0][wid * 1024 + 512]);
    gl16(sAl,       &S[0][1][wid * 1024]);
    gl16(sAl + 512, &S[0][1][wid * 1024 + 512]);
    gl16(sBh,       &S[0][2][wid * 1024]);
    gl16(sBh + 512, &S[0][2][wid * 1024 + 512]);
    gl16(sBl,       &S[0][3][wid * 1024]);
    gl16(sBl + 512, &S[0][3][wid * 1024 + 512]);
    asm volatile("s_waitcnt vmcnt(0)" ::: "memory");
    __builtin_amdgcn_s_barrier();

    for (int t = 0; t < NT; ++t) {
        const unsigned bo = (unsigned)(t & 1) * (4 * PL);
        const int nb = (t & 1) ^ 1;
        const size_t st = (size_t)(t + 1) * TE;
        const bool pf = (t + 1 < NT);

        bf16x8 bh[4], blo[4], a0, a1, l0, l1;

        // ---- phase 0: read B(8) + A mi{0,1}; stage Ah/Al of tile t+1 ----
#pragma unroll
        for (int ni = 0; ni < 4; ++ni) {
            bh[ni]  = ldsr(pB + bo + 2 * PL + ni * 1024);
            blo[ni] = ldsr(pB + bo + 3 * PL + ni * 1024);
        }
        a0 = ldsr(pA + bo);        l0 = ldsr(pA + bo + PL);
        a1 = ldsr(pA + bo + 1024); l1 = ldsr(pA + bo + PL + 1024);
        if (pf) {
            gl16(sAh + st,       &S[nb][0][wid * 1024]);
            gl16(sAh + st + 512, &S[nb][0][wid * 1024 + 512]);
            gl16(sAl + st,       &S[nb][1][wid * 1024]);
            gl16(sAl + st + 512, &S[nb][1][wid * 1024 + 512]);
        }
        PHASE_PRE();
        CLUSTER(0, 1);
        PHASE_POST();

        // ---- phase 1: read A mi{2,3}; stage Bh/Bl of tile t+1 ----
        a0 = ldsr(pA + bo + 2 * 1024); l0 = ldsr(pA + bo + PL + 2 * 1024);
        a1 = ldsr(pA + bo + 3 * 1024); l1 = ldsr(pA + bo + PL + 3 * 1024);
        if (pf) {
            gl16(sBh + st,       &S[nb][2][wid * 1024]);
            gl16(sBh + st + 512, &S[nb][2][wid * 1024 + 512]);
            gl16(sBl + st,       &S[nb][3][wid * 1024]);
            gl16(sBl + st + 512, &S[nb][3][wid * 1024 + 512]);
        }
        PHASE_PRE();
        CLUSTER(2, 3);
        PHASE_POST();

        // ---- phase 2: read A mi{4,5} ----
        a0 = ldsr(pA + bo + 4 * 1024); l0 = ldsr(pA + bo + PL + 4 * 1024);
        a1 = ldsr(pA + bo + 5 * 1024); l1 = ldsr(pA + bo + PL + 5 * 1024);
        PHASE_PRE();
        CLUSTER(4, 5);
        PHASE_POST();

        // ---- phase 3: read A mi{6,7}; tile-end drain ----
        a0 = ldsr(pA + bo + 6 * 1024); l0 = ldsr(pA + bo + PL + 6 * 1024);
        a1 = ldsr(pA + bo + 7 * 1024); l1 = ldsr(pA + bo + PL + 7 * 1024);
        PHASE_PRE();
        CLUSTER(6, 7);
        __builtin_amdgcn_s_setprio(0);
        asm volatile("s_waitcnt vmcnt(0)" ::: "memory");  // own t+1 staging done
        __builtin_amdgcn_s_barrier();                     // all waves drained
    }

    // ---- epilogue: C/D layout col=lane&15, row=(lane>>4)*4+reg ----
    const int row0 = bm * 256 + wr + lg * 4;
    const int col0 = bn * 256 + wc + lr;
    float bv[4];
#pragma unroll
    for (int ni = 0; ni < 4; ++ni) bv[ni] = bias[col0 + ni * 16];
#pragma unroll
    for (int mi = 0; mi < 8; ++mi)
#pragma unroll
        for (int ni = 0; ni < 4; ++ni) {
            float* o = out + (size_t)(row0 + mi * 16) * NN + col0 + ni * 16;
#pragma unroll
            for (int r = 0; r < 4; ++r)
                o[(size_t)r * NN] = acc[mi][ni][r] + bv[ni];
        }
}

// ---------------------------------------------------------------------------
// Fallback (ws too small): naive fp32 GEMM.
// ---------------------------------------------------------------------------
__global__ __launch_bounds__(256) void qlinear_naive(const float* __restrict__ x,
                                                     const float* __restrict__ w,
                                                     const float* __restrict__ bias,
                                                     float* __restrict__ out) {
    int n = blockIdx.x * 64 + (threadIdx.x & 63);
    int m = blockIdx.y * 4 + (threadIdx.x >> 6);
    const float4* xr = (const float4*)(x + (size_t)m * KK);
    const float4* wr = (const float4*)(w + (size_t)n * KK);
    float s = 0.f;
    for (int k = 0; k < KK / 4; ++k) {
        float4 a = xr[k], b = wr[k];
        s += a.x * b.x + a.y * b.y + a.z * b.z + a.w * b.w;
    }
    out[(size_t)m * NN + n] = s + bias[n];
}

extern "C" void kernel_launch(void* const* d_in, const int* in_sizes, int n_in,
                              void* d_out, int out_size, void* d_ws, size_t ws_size,
                              hipStream_t stream) {
    (void)in_sizes; (void)n_in; (void)out_size;
    const float* x = (const float*)d_in[0];
    const float* w = (const float*)d_in[1];
    const float* bias = (const float*)d_in[2];
    float* out = (float*)d_out;

    const size_t xcnt = (size_t)MM * KK;   // 8,388,608
    const size_t wcnt = (size_t)NN * KK;   // 4,194,304
    const size_t need = (xcnt + wcnt) * 2 * sizeof(unsigned short);  // 48 MiB

    if (ws_size >= need) {
        unsigned short* xh = (unsigned short*)d_ws;
        unsigned short* xl = xh + xcnt;
        unsigned short* wh = xl + xcnt;
        unsigned short* wl = wh + wcnt;
        split_pack<<<(int)(MM * 128 / 256), 256, 0, stream>>>(x, xh, xl, MM * 128);
        split_pack<<<(int)(NN * 128 / 256), 256, 0, stream>>>(w, wh, wl, NN * 128);
        qlinear_mfma<<<512, 512, 0, stream>>>(xh, xl, wh, wl, bias, out);
    } else {
        dim3 grid(NN / 64, MM / 4);
        qlinear_naive<<<grid, 256, 0, stream>>>(x, w, bias, out);
    }
}

// Round 3
// 327.252 us; speedup vs baseline: 1.0628x; 1.0246x over previous
//
#include <hip/hip_runtime.h>
#include <stdint.h>

// out[8192,4096] = x[8192,1024] @ W[4096,1024]^T + bias (all fp32; float_quantize
// exp=8/man=23 is an identity). Split-bf16 emulation: hi*hi + lo*hi + hi*lo,
// fp32 MFMA accumulate.
#define MM 8192
#define KK 1024
#define NN 4096
#define NT 32            // K tiles (BK=32)
#define TEA 8192         // A plane-tile elems (256 rows x 32 k)
#define TEB 4096         // B plane-tile elems (128 rows x 32 k)
#define BUFE 24576       // elems per LDS buffer (Ah16K+Al16K+Bh8K+Bl8K = 48KB)

typedef float f32x4 __attribute__((ext_vector_type(4)));
typedef __bf16 bf16x8 __attribute__((ext_vector_type(8)));
typedef unsigned short u16x8 __attribute__((ext_vector_type(8)));

static __device__ __forceinline__ unsigned short f2bf(float f) {
    unsigned int u = __builtin_bit_cast(unsigned int, f);
    u += 0x7fffu + ((u >> 16) & 1u);    // RNE fp32->bf16 (finite inputs)
    return (unsigned short)(u >> 16);
}
static __device__ __forceinline__ float bf2f(unsigned short s) {
    unsigned int u = ((unsigned int)s) << 16;
    return __builtin_bit_cast(float, u);
}

// ---------------------------------------------------------------------------
// Split fp32 -> (hi,lo) bf16 planes, pre-tiled + bank-spread-permuted in the
// exact linear order the GEMM's global_load_lds staging consumes (rule 21).
// Output octet j: plane p=j>>spl (spl=log2(R*4)), slot s=j&(R*4-1), r=s>>2,
// contains source k-octet oct=(s&3)^((r>>1)&3) of row bt*R+r, k-tile kt.
// Writes perfectly linear 16B/thread; reads 128B-coalesced in 4-thread groups.
// ---------------------------------------------------------------------------
__global__ __launch_bounds__(256) void split_pack(const float* __restrict__ in,
        unsigned short* __restrict__ hi, unsigned short* __restrict__ lo,
        int R, int spl, int total) {
    int j = blockIdx.x * 256 + threadIdx.x;
    if (j >= total) return;
    int p = j >> spl;                    // plane index = bt*NT + kt
    int s = j & ((R * 4) - 1);
    int r = s >> 2;
    int oct = (s & 3) ^ ((r >> 1) & 3);
    int bt = p >> 5, kt = p & 31;        // NT = 32
    size_t src = (size_t)(bt * R + r) * KK + kt * 32 + oct * 8;
    const float4* sp = (const float4*)(in + src);
    float4 a = sp[0], b = sp[1];
    float v[8] = {a.x, a.y, a.z, a.w, b.x, b.y, b.z, b.w};
    u16x8 h, l;
#pragma unroll
    for (int q = 0; q < 8; ++q) {
        unsigned short hb = f2bf(v[q]);
        h[q] = hb;
        l[q] = f2bf(v[q] - bf2f(hb));    // exact residual, ~8 more bits
    }
    *(u16x8*)(hi + (size_t)j * 8) = h;
    *(u16x8*)(lo + (size_t)j * 8) = l;
}

// ---------------------------------------------------------------------------
// helpers
// ---------------------------------------------------------------------------
static __device__ __forceinline__ bf16x8 ldsr(unsigned addr) {
    bf16x8 r;
    asm volatile("ds_read_b128 %0, %1" : "=v"(r) : "v"(addr));
    return r;
}
static __device__ __forceinline__ void gl16(const unsigned short* g, unsigned short* l) {
    __builtin_amdgcn_global_load_lds(
        (__attribute__((address_space(1))) void*)(void*)g,
        (__attribute__((address_space(3))) void*)(void*)l, 16, 0, 0);
}
static __device__ __forceinline__ void mf(f32x4& d, bf16x8 a, bf16x8 b) {
    d = __builtin_amdgcn_mfma_f32_16x16x32_bf16(a, b, d, 0, 0, 0);
}

// ---------------------------------------------------------------------------
// 256x128 tile, BK=32, 8 waves (2M x 4N, per-wave 128x32 = acc[8][2]).
// TRIPLE-buffered LDS (3 x 48KB): stage tile t+2 during tile t -> counted
// vmcnt(6) per tile, never 0 in the main loop (T4). One barrier per tile,
// 48 MFMA between barriers, counted lgkmcnt(8) so the mi4-7 frag reads fly
// under the mi0-3 MFMA group. Product-major MFMA order: same-acc distance 8.
// ---------------------------------------------------------------------------
__global__ __launch_bounds__(512, 1) void qlinear_mfma(
        const unsigned short* __restrict__ Ah, const unsigned short* __restrict__ Al,
        const unsigned short* __restrict__ Bh, const unsigned short* __restrict__ Bl,
        const float* __restrict__ bias, float* __restrict__ out) {
    __shared__ __attribute__((aligned(16))) unsigned short S[3 * BUFE];

    // XCD-bijective swizzle (1024 % 8 == 0). 128 consecutive wg per XCD =
    // 4 bm-groups x 32 bn: each A panel (1MB) L2-resident across its 32 wg.
    int bid = blockIdx.x;
    int wg = (bid & 7) * 128 + (bid >> 3);
    int bm = wg >> 5, bn = wg & 31;      // 32 x 32 tiles

    const int tix = threadIdx.x;
    const int lane = tix & 63, wid = tix >> 6;
    const int wr = (wid >> 2) * 128;     // wave M offset (0/128)
    const int wc = (wid & 3) * 32;       // wave N offset (0/32/64/96)
    const int lr = lane & 15, lg = lane >> 4;
    const int xorv = (lr >> 1) & 3;      // bank-spread xor (row bits 1-2)

    const unsigned lb = (unsigned)(uintptr_t)(__attribute__((address_space(3))) void*)&S[0];
    // within-plane byte offsets of this lane's fragment base (frag mi/ni at +1024*i)
    const unsigned pA = (unsigned)(((wr + lr) * 32 + (lg ^ xorv) * 8) * 2);
    const unsigned pB = (unsigned)(((wc + lr) * 32 + (lg ^ xorv) * 8) * 2);

    // staging source pointers (pre-packed planes, per-wave linear chunk)
    const unsigned short* pAh = Ah + (size_t)bm * NT * TEA + wid * 1024 + lane * 8;
    const unsigned short* pAl = Al + (size_t)bm * NT * TEA + wid * 1024 + lane * 8;
    const unsigned short* pBh = Bh + (size_t)bn * NT * TEB + wid * 512 + lane * 8;
    const unsigned short* pBl = Bl + (size_t)bn * NT * TEB + wid * 512 + lane * 8;

#define STAGE(T, SOF) do {                                                   \
        unsigned short* db = &S[(SOF)];                                      \
        size_t ta = (size_t)(T) * TEA, tb = (size_t)(T) * TEB;               \
        gl16(pAh + ta,       db + wid * 1024);                               \
        gl16(pAh + ta + 512, db + wid * 1024 + 512);                         \
        gl16(pAl + ta,       db + 8192 + wid * 1024);                        \
        gl16(pAl + ta + 512, db + 8192 + wid * 1024 + 512);                  \
        gl16(pBh + tb,       db + 16384 + wid * 512);                        \
        gl16(pBl + tb,       db + 20480 + wid * 512);                        \
    } while (0)

    f32x4 acc[8][2];
#pragma unroll
    for (int mi = 0; mi < 8; ++mi) {
        acc[mi][0] = (f32x4){0.f, 0.f, 0.f, 0.f};
        acc[mi][1] = (f32x4){0.f, 0.f, 0.f, 0.f};
    }

    // prologue: stage tiles 0 and 1 (12 loads in flight)
    STAGE(0, 0);
    STAGE(1, BUFE);

    unsigned roff = 0;            // read buffer elem offset  (t%3 * BUFE)
    unsigned soff = 2 * BUFE;     // stage buffer elem offset ((t+2)%3 * BUFE)

    for (int t = 0; t < NT; ++t) {
        // T4: counted wait — oldest 6 (this tile's) done, next tile's stay in flight
        if (t == NT - 1) asm volatile("s_waitcnt vmcnt(0)" ::: "memory");
        else             asm volatile("s_waitcnt vmcnt(6)" ::: "memory");
        __builtin_amdgcn_s_barrier();

        if (t < NT - 2) STAGE(t + 2, soff);   // issue next-next tile first (T14)

        const unsigned ab = lb + roff * 2 + pA;          // Ah base
        const unsigned bb = lb + roff * 2 + 32768 + pB;  // Bh base (byte 16384*2)

        bf16x8 ah[8], al[8], bh2[2], bl2[2];
        // first 12 reads: B frags + A mi0-3
        bh2[0] = ldsr(bb);          bh2[1] = ldsr(bb + 1024);
        bl2[0] = ldsr(bb + 8192);   bl2[1] = ldsr(bb + 8192 + 1024);
#pragma unroll
        for (int mi = 0; mi < 4; ++mi) {
            ah[mi] = ldsr(ab + mi * 1024);
            al[mi] = ldsr(ab + 16384 + mi * 1024);
        }
        // next 8 reads: A mi4-7 (fly under group-1 MFMA)
#pragma unroll
        for (int mi = 4; mi < 8; ++mi) {
            ah[mi] = ldsr(ab + mi * 1024);
            al[mi] = ldsr(ab + 16384 + mi * 1024);
        }

        asm volatile("s_waitcnt lgkmcnt(8)" ::: "memory");  // first 12 done
        __builtin_amdgcn_sched_barrier(0);                  // rule 18
        __builtin_amdgcn_s_setprio(1);
        // group 1: mi0-3, product-major (same-acc reuse distance = 8)
#pragma unroll
        for (int mi = 0; mi < 4; ++mi) { mf(acc[mi][0], ah[mi], bh2[0]); mf(acc[mi][1], ah[mi], bh2[1]); }
#pragma unroll
        for (int mi = 0; mi < 4; ++mi) { mf(acc[mi][0], al[mi], bh2[0]); mf(acc[mi][1], al[mi], bh2[1]); }
#pragma unroll
        for (int mi = 0; mi < 4; ++mi) { mf(acc[mi][0], ah[mi], bl2[0]); mf(acc[mi][1], ah[mi], bl2[1]); }

        asm volatile("s_waitcnt lgkmcnt(0)" ::: "memory");  // mi4-7 frags ready
        __builtin_amdgcn_sched_barrier(0);
        // group 2: mi4-7
#pragma unroll
        for (int mi = 4; mi < 8; ++mi) { mf(acc[mi][0], ah[mi], bh2[0]); mf(acc[mi][1], ah[mi], bh2[1]); }
#pragma unroll
        for (int mi = 4; mi < 8; ++mi) { mf(acc[mi][0], al[mi], bh2[0]); mf(acc[mi][1], al[mi], bh2[1]); }
#pragma unroll
        for (int mi = 4; mi < 8; ++mi) { mf(acc[mi][0], ah[mi], bl2[0]); mf(acc[mi][1], ah[mi], bl2[1]); }
        __builtin_amdgcn_s_setprio(0);
        __builtin_amdgcn_sched_barrier(0);

        roff = (roff == 2 * BUFE) ? 0u : roff + BUFE;
        soff = (soff == 2 * BUFE) ? 0u : soff + BUFE;
    }
#undef STAGE

    // epilogue: C/D layout col=lane&15, row=(lane>>4)*4+reg (m89-verified)
    const int row0 = bm * 256 + wr + lg * 4;
    const int col0 = bn * 128 + wc + lr;
    float bv[2] = {bias[col0], bias[col0 + 16]};
#pragma unroll
    for (int mi = 0; mi < 8; ++mi)
#pragma unroll
        for (int ni = 0; ni < 2; ++ni) {
            float* o = out + (size_t)(row0 + mi * 16) * NN + col0 + ni * 16;
#pragma unroll
            for (int r = 0; r < 4; ++r)
                o[(size_t)r * NN] = acc[mi][ni][r] + bv[ni];
        }
}

// ---------------------------------------------------------------------------
// Fallback (ws too small): naive fp32 GEMM.
// ---------------------------------------------------------------------------
__global__ __launch_bounds__(256) void qlinear_naive(const float* __restrict__ x,
                                                     const float* __restrict__ w,
                                                     const float* __restrict__ bias,
                                                     float* __restrict__ out) {
    int n = blockIdx.x * 64 + (threadIdx.x & 63);
    int m = blockIdx.y * 4 + (threadIdx.x >> 6);
    const float4* xr = (const float4*)(x + (size_t)m * KK);
    const float4* wr = (const float4*)(w + (size_t)n * KK);
    float s = 0.f;
    for (int k = 0; k < KK / 4; ++k) {
        float4 a = xr[k], b = wr[k];
        s += a.x * b.x + a.y * b.y + a.z * b.z + a.w * b.w;
    }
    out[(size_t)m * NN + n] = s + bias[n];
}

extern "C" void kernel_launch(void* const* d_in, const int* in_sizes, int n_in,
                              void* d_out, int out_size, void* d_ws, size_t ws_size,
                              hipStream_t stream) {
    (void)in_sizes; (void)n_in; (void)out_size;
    const float* x = (const float*)d_in[0];
    const float* w = (const float*)d_in[1];
    const float* bias = (const float*)d_in[2];
    float* out = (float*)d_out;

    const size_t xcnt = (size_t)MM * KK;   // 8,388,608
    const size_t wcnt = (size_t)NN * KK;   // 4,194,304
    const size_t need = (xcnt + wcnt) * 2 * sizeof(unsigned short);  // 48 MiB

    if (ws_size >= need) {
        unsigned short* xh = (unsigned short*)d_ws;
        unsigned short* xl = xh + xcnt;
        unsigned short* wh = xl + xcnt;
        unsigned short* wl = wh + wcnt;
        // A planes: R=256 rows/tile (spl=10); B planes: R=128 (spl=9)
        split_pack<<<(int)(xcnt / 8 / 256), 256, 0, stream>>>(x, xh, xl, 256, 10, (int)(xcnt / 8));
        split_pack<<<(int)(wcnt / 8 / 256), 256, 0, stream>>>(w, wh, wl, 128, 9, (int)(wcnt / 8));
        qlinear_mfma<<<1024, 512, 0, stream>>>(xh, xl, wh, wl, bias, out);
    } else {
        dim3 grid(NN / 64, MM / 4);
        qlinear_naive<<<grid, 256, 0, stream>>>(x, w, bias, out);
    }
}